// Round 10
// baseline (365.056 us; speedup 1.0000x reference)
//
#include <hip/hip_runtime.h>
#include <hip/hip_bf16.h>
#include <math.h>

#define N_TOK 8192
#define DDIM  1024
#define HDIM  4096
#define NBLK  512

typedef __bf16 bf16x8 __attribute__((ext_vector_type(8)));
typedef __bf16 bf16x4 __attribute__((ext_vector_type(4)));
typedef float  floatx4 __attribute__((ext_vector_type(4)));

__device__ __forceinline__ float wave_reduce_sum(float v) {
#pragma unroll
    for (int off = 32; off > 0; off >>= 1) v += __shfl_down(v, off, 64);
    return v;
}

__device__ __forceinline__ void gload_lds16(const void* g, void* l) {
    __builtin_amdgcn_global_load_lds((const __attribute__((address_space(1))) void*)g,
                                     (__attribute__((address_space(3))) void*)l,
                                     16, 0, 0);
}

// Branchless gelu via A&S 7.1.26 erf (max err 1.5e-7), ~13 VALU ops.
__device__ __forceinline__ float fast_gelu(float x) {
    float ax = fabsf(x);
    float z  = ax * 0.70710678118654752f;
    float t  = __builtin_amdgcn_rcpf(fmaf(0.3275911f, z, 1.0f));
    float p  = fmaf(fmaf(fmaf(fmaf(1.061405429f, t, -1.453152027f),
                              t, 1.421413741f),
                         t, -0.284496736f),
                    t, 0.254829592f);
    p *= t;
    float e = __expf(-z * z);
    float E = fmaf(-p, e, 1.0f);
    return 0.5f * fmaf(ax, E, x);
}

__device__ __forceinline__ float fast_softplus(float r) {
    return __logf(fmaf(1.0f, __expf(r), 1.0f));
}

// ---------------------------------------------------------------------------
// Fused prep kernel: unit rows / LN+x-cast / W casts.  All paths float4.
// ---------------------------------------------------------------------------
__device__ __forceinline__ void cast1024(const float* __restrict__ s,
                                         __bf16* __restrict__ d,
                                         size_t off, int t) {
    float4 v = ((const float4*)(s + off))[t];
    bf16x4 o;
    o.x = (__bf16)v.x; o.y = (__bf16)v.y;
    o.z = (__bf16)v.z; o.w = (__bf16)v.w;
    ((bf16x4*)(d + off))[t] = o;
}

__global__ __launch_bounds__(256) void prep_kernel(
        const float* __restrict__ x,
        const float* __restrict__ ln_g, const float* __restrict__ ln_b,
        const float* __restrict__ W1,   const float* __restrict__ W2,
        const float* __restrict__ router_W,
        const float* __restrict__ rawU, const float* __restrict__ rawV,
        __bf16* __restrict__ xb,  __bf16* __restrict__ lnb,
        __bf16* __restrict__ w1b, __bf16* __restrict__ w2b,
        __bf16* __restrict__ rwb,
        float* __restrict__ unitU, float* __restrict__ unitV) {
    int b = blockIdx.x;
    int t = threadIdx.x;

    if (b < 1024) {
        const float* src = (b < NBLK) ? rawU + (size_t)b * DDIM
                                      : rawV + (size_t)(b - NBLK) * DDIM;
        float* dst = (b < NBLK) ? unitU + (size_t)b * DDIM
                                : unitV + (size_t)(b - NBLK) * DDIM;
        float4 v = ((const float4*)src)[t];
        float ss = v.x * v.x + v.y * v.y + v.z * v.z + v.w * v.w;
        __shared__ float red[4];
        ss = wave_reduce_sum(ss);
        if ((t & 63) == 0) red[t >> 6] = ss;
        __syncthreads();
        float tot = red[0] + red[1] + red[2] + red[3];
        float inv = 1.f / fmaxf(sqrtf(tot), 1e-6f);
        float4 o;
        o.x = v.x * inv; o.y = v.y * inv; o.z = v.z * inv; o.w = v.w * inv;
        ((float4*)dst)[t] = o;
    } else if (b < 9216) {
        int n = b - 1024;
        float4 v = ((const float4*)(x + (size_t)n * DDIM))[t];
        float s1 = v.x + v.y + v.z + v.w;
        float s2 = v.x * v.x + v.y * v.y + v.z * v.z + v.w * v.w;
        __shared__ float r1[4], r2[4];
        s1 = wave_reduce_sum(s1);
        s2 = wave_reduce_sum(s2);
        if ((t & 63) == 0) { r1[t >> 6] = s1; r2[t >> 6] = s2; }
        __syncthreads();
        float mu  = (r1[0] + r1[1] + r1[2] + r1[3]) * (1.f / DDIM);
        float var = (r2[0] + r2[1] + r2[2] + r2[3]) * (1.f / DDIM) - mu * mu;
        float rstd = rsqrtf(var + 1e-5f);
        float4 g  = ((const float4*)ln_g)[t];
        float4 bb = ((const float4*)ln_b)[t];
        bf16x4 o, xo;
        o.x = (__bf16)((v.x - mu) * rstd * g.x + bb.x);
        o.y = (__bf16)((v.y - mu) * rstd * g.y + bb.y);
        o.z = (__bf16)((v.z - mu) * rstd * g.z + bb.z);
        o.w = (__bf16)((v.w - mu) * rstd * g.w + bb.w);
        xo.x = (__bf16)v.x; xo.y = (__bf16)v.y;
        xo.z = (__bf16)v.z; xo.w = (__bf16)v.w;
        ((bf16x4*)(lnb + (size_t)n * DDIM))[t] = o;
        ((bf16x4*)(xb  + (size_t)n * DDIM))[t] = xo;
    } else if (b < 13312) {
        cast1024(W1, w1b, (size_t)(b - 9216) * 1024, t);
    } else if (b < 17408) {
        cast1024(W2, w2b, (size_t)(b - 13312) * 1024, t);
    } else {
        cast1024(router_W, rwb, (size_t)(b - 17408) * 1024, t);
    }
}

// ---------------------------------------------------------------------------
// 2-phase 128xBN NT GEMM — router only (8.6 GFLOP).
// MODE 0: D = fast_softplus(clip(acc+bias)) -> fp32
// ---------------------------------------------------------------------------
template <int MODE, int BN>
__global__ __launch_bounds__(256) void mfma_gemm(const __bf16* __restrict__ A,
                                                 const __bf16* __restrict__ B,
                                                 const float* __restrict__ bias,
                                                 void* __restrict__ Cv,
                                                 int M, int Nn, int Kk) {
    constexpr int NJ  = BN / 32;
    constexpr int NQB = BN / 64;
    __shared__ __align__(16) __bf16 As[2][128 * 32];
    __shared__ __align__(16) __bf16 Bs[2][BN * 32];

    const int t    = threadIdx.x;
    const int lane = t & 63;
    const int wave = t >> 6;
    const int wm   = wave >> 1, wn = wave & 1;
    const int lr   = lane & 15, quad = lane >> 4;
    const int m0   = blockIdx.x * 128;
    const int n0   = blockIdx.y * BN;

    const int ca0 = t & 3;
    const __bf16* Ag[2];
    const __bf16* Bg[NQB];
    int ldsOffA[2], ldsOffB[NQB];
#pragma unroll
    for (int q = 0; q < 2; q++) {
        int idx = q * 256 + t;
        Ag[q]      = A + (size_t)(m0 + (idx >> 2)) * Kk + ca0 * 8;
        ldsOffA[q] = idx * 8;
    }
#pragma unroll
    for (int q = 0; q < NQB; q++) {
        int idx = q * 256 + t;
        Bg[q]      = B + (size_t)(n0 + (idx >> 2)) * Kk + ca0 * 8;
        ldsOffB[q] = idx * 8;
    }

    int raOff[4], rbOff[NJ];
#pragma unroll
    for (int i = 0; i < 4; i++)
        raOff[i] = (wm * 64 + i * 16 + lr) * 32 + quad * 8;
#pragma unroll
    for (int j = 0; j < NJ; j++)
        rbOff[j] = (wn * (BN / 2) + j * 16 + lr) * 32 + quad * 8;

    floatx4 acc[4][NJ];
#pragma unroll
    for (int i = 0; i < 4; i++)
#pragma unroll
        for (int j = 0; j < NJ; j++) acc[i][j] = (floatx4)0.f;

#pragma unroll
    for (int q = 0; q < 2; q++)   gload_lds16(Ag[q], &As[0][ldsOffA[q]]);
#pragma unroll
    for (int q = 0; q < NQB; q++) gload_lds16(Bg[q], &Bs[0][ldsOffB[q]]);

    const int niter = Kk >> 5;
    for (int it = 0; it < niter; ++it) {
        const int cur = it & 1;
        __syncthreads();
        if (it + 1 < niter) {
            const int nk = (it + 1) << 5;
            const int nb = cur ^ 1;
#pragma unroll
            for (int q = 0; q < 2; q++)   gload_lds16(Ag[q] + nk, &As[nb][ldsOffA[q]]);
#pragma unroll
            for (int q = 0; q < NQB; q++) gload_lds16(Bg[q] + nk, &Bs[nb][ldsOffB[q]]);
        }
        bf16x8 af[4], bfr[NJ];
#pragma unroll
        for (int i = 0; i < 4; i++)  af[i]  = *(const bf16x8*)&As[cur][raOff[i]];
#pragma unroll
        for (int j = 0; j < NJ; j++) bfr[j] = *(const bf16x8*)&Bs[cur][rbOff[j]];
#pragma unroll
        for (int i = 0; i < 4; i++)
#pragma unroll
            for (int j = 0; j < NJ; j++)
                acc[i][j] = __builtin_amdgcn_mfma_f32_16x16x32_bf16(af[i], bfr[j],
                                                                    acc[i][j], 0, 0, 0);
    }

    const int mBase = m0 + wm * 64 + quad * 4;
    const int nBase = n0 + wn * (BN / 2) + lr;
#pragma unroll
    for (int i = 0; i < 4; i++) {
#pragma unroll
        for (int j = 0; j < NJ; j++) {
            int n = nBase + j * 16;
#pragma unroll
            for (int r = 0; r < 4; r++) {
                int m = mBase + i * 16 + r;
                float v = acc[i][j][r];
                if (MODE == 0) {
                    float rr = v + bias[n];
                    rr = fminf(fmaxf(rr, -10.f), 10.f);
                    ((float*)Cv)[(size_t)m * Nn + n] = fast_softplus(rr);
                } else if (MODE == 1) {
                    ((__bf16*)Cv)[(size_t)m * Nn + n] = (__bf16)fast_gelu(v);
                } else {
                    ((float*)Cv)[(size_t)m * Nn + n] += v;
                }
            }
        }
    }
}

// ---------------------------------------------------------------------------
// 256x256 8-phase NT GEMM, BK=64, 512 thr = 8 waves (2M x 4N), wave 128x64.
// Snake: P0 MM(0,0)[12 rd], P1 MM(0,1)[4 rd], P2 MM(1,1)[8 rd], P3 MM(1,0)[0]
// = 24 ds_read_b128 / 64 MFMA. LDS XOR swizzle (0 bank conflicts).
// SESSION VERDICT (R1-R9): three counted-vmcnt disciplines, two barrier
// forms, two tile structures, split-K on/off all land in the same band
// (gemm2 105-122us / ~650 TF; gemm1 ~85us / ~810 TF = the documented
// plain-HIP m97-band for this shape). Schedule-invariance indicates hipcc's
// own per-use waitcnt insertion dominates scheduling (rule #18 corollary);
// closing the ~2x to m201's 1563 TF needs .s-level evidence unavailable in
// this loop. This file is the best-measured configuration of the family.
//   SCHED 0: vmcnt(10) at P0/P1/P3; tails (10/8/4), (2/0/0).
//   SCHED 1: lgkmcnt(8) hint at P0; single vmcnt(6) at P3; tails 0.
// MODE 1: D = gelu(acc)->bf16.  MODE 2: atomicAdd fp32 (split-K safe).
// ---------------------------------------------------------------------------
template <int MODE, int SPLITK, int SCHED>
__global__ __launch_bounds__(512, 2) void mfma_gemm8v2(const __bf16* __restrict__ A,
                                                       const __bf16* __restrict__ B,
                                                       void* __restrict__ Cv,
                                                       int M, int Nn, int Kk) {
    __shared__ __align__(16) __bf16 As[2][256 * 64];
    __shared__ __align__(16) __bf16 Bs[2][256 * 64];

    const int t    = threadIdx.x;
    const int lane = t & 63;
    const int wave = t >> 6;
    const int wm   = wave >> 2;        // 0..1
    const int wn   = wave & 3;         // 0..3
    const int lr   = lane & 15, quad = lane >> 4;

    // bijective XCD swizzle (gridDim.x % 8 == 0 by construction)
    const int nbn   = Nn >> 8;
    const int nmb   = M >> 8;
    const int chunk = gridDim.x >> 3;
    const int bid   = blockIdx.x;
    const int wg    = (bid & 7) * chunk + (bid >> 3);
    const int kslc  = wg / (nmb * nbn);
    const int rem   = wg % (nmb * nbn);
    const int m0    = (rem / nbn) * 256;
    const int n0    = (rem % nbn) * 256;
    const int kseg  = Kk / SPLITK;
    const int NT    = kseg >> 6;

    // ---- staging: linear LDS dest, inverse-swizzled global source ----
    const int srow = t >> 3;                               // 0..63
    const int scb  = ((t & 7) << 4) ^ ((srow & 7) << 4);   // swizzled byte col
    const __bf16* aP = A + (size_t)(m0 + srow) * Kk + (size_t)kslc * kseg + (scb >> 1);
    const __bf16* bP = B + (size_t)(n0 + srow) * Kk + (size_t)kslc * kseg + (scb >> 1);
    const int dP = srow * 64 + (t & 7) * 8;                // elems

    // ---- ds-read per-lane offsets (elements), swizzled ----
    int aRd[2], bRd[2];
#pragma unroll
    for (int ks = 0; ks < 2; ks++) {
        int sw = ((ks * 64 + quad * 16) ^ ((lr & 7) << 4)) >> 1;
        aRd[ks] = (wm * 64 + lr) * 64 + sw;
        bRd[ks] = (wn * 32 + lr) * 64 + sw;
    }

    floatx4 acc[8][4];
#pragma unroll
    for (int i = 0; i < 8; i++)
#pragma unroll
        for (int j = 0; j < 4; j++) acc[i][j] = (floatx4)0.f;

    bf16x8 af[4][2];        // A frags, current m-strip
    bf16x8 bfr0[2][2];      // B frags, n-strip 0 (held across tile)
    bf16x8 bfr1[2][2];      // B frags, n-strip 1

#define STAGE_A(KT, MH, BUF)                                                        \
    _Pragma("unroll") for (int q = 0; q < 2; q++)                                   \
        gload_lds16(aP + (size_t)(KT) * 64 + (size_t)(q * 64 + (MH) * 128) * Kk,    \
                    &As[BUF][dP + (q * 64 + (MH) * 128) * 64])
#define STAGE_B(KT, NH, BUF)                                                        \
    _Pragma("unroll") for (int q = 0; q < 2; q++)                                   \
        gload_lds16(bP + (size_t)(KT) * 64 + (size_t)(q * 64 + (NH) * 128) * Kk,    \
                    &Bs[BUF][dP + (q * 64 + (NH) * 128) * 64])
#define LDA(CUR, MH)                                                                \
    _Pragma("unroll") for (int ii = 0; ii < 4; ii++)                                \
    _Pragma("unroll") for (int ks = 0; ks < 2; ks++)                                \
        af[ii][ks] = *(const bf16x8*)&As[CUR][aRd[ks] + (MH) * 8192 + ii * 1024]
#define LDB(CUR, NH, DST)                                                           \
    _Pragma("unroll") for (int jj = 0; jj < 2; jj++)                                \
    _Pragma("unroll") for (int ks = 0; ks < 2; ks++)                                \
        DST[jj][ks] = *(const bf16x8*)&Bs[CUR][bRd[ks] + ((NH) * 128 + jj * 16) * 64]
#define MM(MH, NH, BFR)                                                             \
    _Pragma("unroll") for (int ii = 0; ii < 4; ii++)                                \
    _Pragma("unroll") for (int jj = 0; jj < 2; jj++)                                \
    _Pragma("unroll") for (int ks = 0; ks < 2; ks++)                                \
        acc[(MH) * 4 + ii][(NH) * 2 + jj] =                                         \
            __builtin_amdgcn_mfma_f32_16x16x32_bf16(                                \
                af[ii][ks], BFR[jj][ks], acc[(MH) * 4 + ii][(NH) * 2 + jj], 0, 0, 0)
#define VWAIT(NSTR) asm volatile("s_waitcnt vmcnt(" NSTR ")" ::: "memory")
#define LHINT()     asm volatile("s_waitcnt lgkmcnt(8)" ::: "memory")
#define WAITL()     asm volatile("s_waitcnt lgkmcnt(0)" ::: "memory")
#define BARR()      asm volatile("s_barrier" ::: "memory")
#define PRIO1()     __builtin_amdgcn_s_setprio(1)
#define PRIO0()     __builtin_amdgcn_s_setprio(0)

// R3-style: three counted waits per tile.
#define TILE3(KT, CUR, ST1, ST2, VM0, VM1, VM3)                                     \
    do {                                                                            \
        LDA(CUR, 0); LDB(CUR, 0, bfr0);                                             \
        if (ST1) { STAGE_A((KT) + 1, 1, ((KT) + 1) & 1); }                          \
        VWAIT(VM0); BARR(); WAITL();                                                \
        PRIO1(); MM(0, 0, bfr0); PRIO0(); BARR();                                   \
        LDB(CUR, 1, bfr1);                                                          \
        if (ST2) { STAGE_A((KT) + 2, 0, (KT) & 1); }                                \
        VWAIT(VM1); BARR(); WAITL();                                                \
        PRIO1(); MM(0, 1, bfr1); PRIO0(); BARR();                                   \
        LDA(CUR, 1);                                                                \
        if (ST2) { STAGE_B((KT) + 2, 0, (KT) & 1); }                                \
        BARR(); WAITL();                                                            \
        PRIO1(); MM(1, 1, bfr1); PRIO0(); BARR();                                   \
        if (ST2) { STAGE_B((KT) + 2, 1, (KT) & 1); }                                \
        VWAIT(VM3); BARR();                                                         \
        PRIO1(); MM(1, 0, bfr0); PRIO0(); BARR();                                   \
    } while (0)

// R4-style: single counted wait per tile at P3, lgkm hint at the 12-read phase.
#define TILE1(KT, CUR, ST1, ST2, VM)                                                \
    do {                                                                            \
        LDA(CUR, 0); LDB(CUR, 0, bfr0);                                             \
        if (ST1) { STAGE_A((KT) + 1, 1, ((KT) + 1) & 1); }                          \
        LHINT(); BARR(); WAITL();                                                   \
        PRIO1(); MM(0, 0, bfr0); PRIO0(); BARR();                                   \
        LDB(CUR, 1, bfr1);                                                          \
        if (ST2) { STAGE_A((KT) + 2, 0, (KT) & 1); }                                \
        BARR(); WAITL();                                                            \
        PRIO1(); MM(0, 1, bfr1); PRIO0(); BARR();                                   \
        LDA(CUR, 1);                                                                \
        if (ST2) { STAGE_B((KT) + 2, 0, (KT) & 1); }                                \
        BARR(); WAITL();                                                            \
        PRIO1(); MM(1, 1, bfr1); PRIO0(); BARR();                                   \
        if (ST2) { STAGE_B((KT) + 2, 1, (KT) & 1); }                                \
        VWAIT(VM); BARR();                                                          \
        PRIO1(); MM(1, 0, bfr0); PRIO0(); BARR();                                   \
    } while (0)

    // prologue: 7 half-tiles in consumption order [A0 B0 B1 A1]_t0 [A0 B0 B1]_t1
    STAGE_A(0, 0, 0); STAGE_B(0, 0, 0); STAGE_B(0, 1, 0); STAGE_A(0, 1, 0);
    STAGE_A(1, 0, 1); STAGE_B(1, 0, 1); STAGE_B(1, 1, 1);
    if (SCHED == 0) { VWAIT("10"); } else { VWAIT("6"); }
    BARR();

    if (SCHED == 0) {
        for (int kt = 0; kt < NT - 2; ++kt)
            TILE3(kt, kt & 1, true, true, "10", "10", "10");
        TILE3(NT - 2, (NT - 2) & 1, true, false, "10", "8", "4");
        TILE3(NT - 1, (NT - 1) & 1, false, false, "2", "0", "0");
    } else {
        for (int kt = 0; kt < NT - 2; ++kt)
            TILE1(kt, kt & 1, true, true, "6");
        TILE1(NT - 2, (NT - 2) & 1, true, false, "0");
        TILE1(NT - 1, (NT - 1) & 1, false, false, "0");
    }

#undef STAGE_A
#undef STAGE_B
#undef LDA
#undef LDB
#undef MM
#undef VWAIT
#undef LHINT
#undef WAITL
#undef BARR
#undef PRIO1
#undef PRIO0
#undef TILE3
#undef TILE1

    // ---- epilogue ----
#pragma unroll
    for (int i = 0; i < 8; i++) {
        const int mh = i >> 2, ii = i & 3;
#pragma unroll
        for (int j = 0; j < 4; j++) {
            const int nh = j >> 1, jj = j & 1;
            const int n = n0 + nh * 128 + wn * 32 + jj * 16 + lr;
#pragma unroll
            for (int r = 0; r < 4; r++) {
                const int m = m0 + mh * 128 + wm * 64 + ii * 16 + quad * 4 + r;
                const float v = acc[i][j][r];
                if (MODE == 1) {
                    ((__bf16*)Cv)[(size_t)m * Nn + n] = (__bf16)fast_gelu(v);
                } else {
                    atomicAdd(&((float*)Cv)[(size_t)m * Nn + n], v);
                }
            }
        }
    }
}

// ---------------------------------------------------------------------------
// Fused top-8 + dynamic path: one block (256 thr) per token. float4 loads.
// ---------------------------------------------------------------------------
__global__ __launch_bounds__(256) void topk_dyn_kernel(
        const float* __restrict__ alpha,
        const float* __restrict__ x,
        const float* __restrict__ unitU,
        const float* __restrict__ unitV,
        const float* __restrict__ gamma,
        float* __restrict__ out) {
    int n = blockIdx.x;
    int t = threadIdx.x;
    int lane = t & 63, wid = t >> 6;

    __shared__ int   sidx[8];
    __shared__ float shz[8];
    __shared__ float red[8][4];
    __shared__ float hz[8];

    if (wid == 0) {
        const float* row = alpha + (size_t)n * NBLK;
        float v[8];
#pragma unroll
        for (int i = 0; i < 8; i++) v[i] = row[lane + i * 64];
        float topv[8];
        int   topi[8];
        for (int s = 0; s < 8; s++) {
            float bv = v[0]; int bi = 0;
#pragma unroll
            for (int i = 1; i < 8; i++)
                if (v[i] > bv) { bv = v[i]; bi = i; }
            int gidx = lane + bi * 64;
#pragma unroll
            for (int off = 1; off < 64; off <<= 1) {
                float ov = __shfl_xor(bv, off, 64);
                int   oi = __shfl_xor(gidx, off, 64);
                if (ov > bv || (ov == bv && oi < gidx)) { bv = ov; gidx = oi; }
            }
            topv[s] = bv; topi[s] = gidx;
            if ((gidx & 63) == lane) v[gidx >> 6] = -1e30f;
        }
        float S = 0.f;
#pragma unroll
        for (int s = 0; s < 8; s++) S += topv[s];
        float zscale = tanhf(S) / (S + 1e-6f);
        if (lane < 8) {
            sidx[lane] = topi[lane];
            shz[lane]  = topv[lane] * zscale;
        }
    }
    __syncthreads();

    float4 xv = ((const float4*)(x + (size_t)n * DDIM))[t];

    float acc[8];
#pragma unroll
    for (int k = 0; k < 8; k++) {
        float4 u = ((const float4*)(unitU + (size_t)sidx[k] * DDIM))[t];
        acc[k] = xv.x * u.x + xv.y * u.y + xv.z * u.z + xv.w * u.w;
    }
#pragma unroll
    for (int k = 0; k < 8; k++) {
        float a = wave_reduce_sum(acc[k]);
        if (lane == 0) red[k][wid] = a;
    }
    __syncthreads();
    if (t < 8) {
        float h = red[t][0] + red[t][1] + red[t][2] + red[t][3];
        hz[t] = h * shz[t];
    }
    __syncthreads();

    float4 s = {0.f, 0.f, 0.f, 0.f};
#pragma unroll
    for (int k = 0; k < 8; k++) {
        float4 v = ((const float4*)(unitV + (size_t)sidx[k] * DDIM))[t];
        float h = hz[k];
        s.x = fmaf(h, v.x, s.x);
        s.y = fmaf(h, v.y, s.y);
        s.z = fmaf(h, v.z, s.z);
        s.w = fmaf(h, v.w, s.w);
    }
    float4 g = ((const float4*)gamma)[t];
    float4 o;
    o.x = s.x * g.x; o.y = s.y * g.y; o.z = s.z * g.z; o.w = s.w * g.w;
    ((float4*)(out + (size_t)n * DDIM))[t] = o;
}

// ---------------------------------------------------------------------------
extern "C" void kernel_launch(void* const* d_in, const int* in_sizes, int n_in,
                              void* d_out, int out_size, void* d_ws, size_t ws_size,
                              hipStream_t stream) {
    const float* x        = (const float*)d_in[0];
    const float* W1       = (const float*)d_in[1];
    const float* W2       = (const float*)d_in[2];
    const float* ln_g     = (const float*)d_in[3];
    const float* ln_b     = (const float*)d_in[4];
    const float* router_W = (const float*)d_in[5];
    const float* router_b = (const float*)d_in[6];
    const float* raw_U    = (const float*)d_in[7];
    const float* raw_V    = (const float*)d_in[8];
    const float* gamma    = (const float*)d_in[9];
    float* out = (float*)d_out;

    char* ws = (char*)d_ws;
    __bf16* lnb   = (__bf16*)(ws);                 // 16,777,216 B
    float*  alpha = (float*)(ws + 16777216u);      // 16,777,216 B
    __bf16* g1    = (__bf16*)(ws);                 // 67,108,864 B (after topk_dyn)
    __bf16* xb    = (__bf16*)(ws + 67108864u);     // 16,777,216 B
    __bf16* w1b   = (__bf16*)(ws + 83886080u);     //  8,388,608 B
    __bf16* w2b   = (__bf16*)(ws + 92274688u);     //  8,388,608 B
    __bf16* rwb   = (__bf16*)(ws + 100663296u);    //  1,048,576 B
    float*  unitU = (float*)(ws + 101711872u);     //  2,097,152 B
    float*  unitV = (float*)(ws + 103809024u);     //  2,097,152 B

    prep_kernel<<<17920, 256, 0, stream>>>(x, ln_g, ln_b, W1, W2, router_W,
                                           raw_U, raw_V, xb, lnb, w1b, w2b, rwb,
                                           unitU, unitV);

    // router: [8192,512] = lnb @ rwb^T, softplus epilogue. BN=64 -> 512 blocks.
    dim3 gR(N_TOK / 128, NBLK / 64);
    mfma_gemm<0, 64><<<gR, 256, 0, stream>>>(lnb, rwb, router_b, (void*)alpha,
                                             N_TOK, NBLK, DDIM);

    // fused top-8 + dynamic path (overwrites out)
    topk_dyn_kernel<<<N_TOK, 256, 0, stream>>>(alpha, x, unitU, unitV, gamma, out);

    // gemm1: g1 = gelu(x @ W1^T) -> bf16. 8-phase 256^2, SCHED=0. grid 512.
    mfma_gemm8v2<1, 1, 0><<<dim3(512), dim3(512), 0, stream>>>(xb, w1b, (void*)g1,
                                                               N_TOK, HDIM, DDIM);

    // gemm2: out += g1 @ W2^T. 8-phase 256^2, split-K=2, SCHED=1.
    // grid 32x4x2 -> 256 blocks, atomicAdd epilogue.
    mfma_gemm8v2<2, 2, 1><<<dim3(256), dim3(512), 0, stream>>>(g1, w2b, (void*)out,
                                                               N_TOK, DDIM, HDIM);
}

// Round 11
// 353.954 us; speedup vs baseline: 1.0314x; 1.0314x over previous
//
#include <hip/hip_runtime.h>
#include <hip/hip_bf16.h>
#include <math.h>

#define N_TOK 8192
#define DDIM  1024
#define HDIM  4096
#define NBLK  512

typedef __bf16 bf16x8 __attribute__((ext_vector_type(8)));
typedef __bf16 bf16x4 __attribute__((ext_vector_type(4)));
typedef float  floatx4 __attribute__((ext_vector_type(4)));

__device__ __forceinline__ float wave_reduce_sum(float v) {
#pragma unroll
    for (int off = 32; off > 0; off >>= 1) v += __shfl_down(v, off, 64);
    return v;
}

// Butterfly: every lane ends with the full sum (no broadcast needed).
__device__ __forceinline__ float wave_allreduce_sum(float v) {
#pragma unroll
    for (int off = 32; off > 0; off >>= 1) v += __shfl_xor(v, off, 64);
    return v;
}

__device__ __forceinline__ void gload_lds16(const void* g, void* l) {
    __builtin_amdgcn_global_load_lds((const __attribute__((address_space(1))) void*)g,
                                     (__attribute__((address_space(3))) void*)l,
                                     16, 0, 0);
}

// Branchless gelu via A&S 7.1.26 erf (max err 1.5e-7), ~13 VALU ops.
__device__ __forceinline__ float fast_gelu(float x) {
    float ax = fabsf(x);
    float z  = ax * 0.70710678118654752f;
    float t  = __builtin_amdgcn_rcpf(fmaf(0.3275911f, z, 1.0f));
    float p  = fmaf(fmaf(fmaf(fmaf(1.061405429f, t, -1.453152027f),
                              t, 1.421413741f),
                         t, -0.284496736f),
                    t, 0.254829592f);
    p *= t;
    float e = __expf(-z * z);
    float E = fmaf(-p, e, 1.0f);
    return 0.5f * fmaf(ax, E, x);
}

__device__ __forceinline__ float fast_softplus(float r) {
    return __logf(fmaf(1.0f, __expf(r), 1.0f));
}

// ---------------------------------------------------------------------------
// Fused prep kernel: unit rows / LN+x-cast / W casts.  All paths float4.
// ---------------------------------------------------------------------------
__device__ __forceinline__ void cast1024(const float* __restrict__ s,
                                         __bf16* __restrict__ d,
                                         size_t off, int t) {
    float4 v = ((const float4*)(s + off))[t];
    bf16x4 o;
    o.x = (__bf16)v.x; o.y = (__bf16)v.y;
    o.z = (__bf16)v.z; o.w = (__bf16)v.w;
    ((bf16x4*)(d + off))[t] = o;
}

__global__ __launch_bounds__(256) void prep_kernel(
        const float* __restrict__ x,
        const float* __restrict__ ln_g, const float* __restrict__ ln_b,
        const float* __restrict__ W1,   const float* __restrict__ W2,
        const float* __restrict__ router_W,
        const float* __restrict__ rawU, const float* __restrict__ rawV,
        __bf16* __restrict__ xb,  __bf16* __restrict__ lnb,
        __bf16* __restrict__ w1b, __bf16* __restrict__ w2b,
        __bf16* __restrict__ rwb,
        float* __restrict__ unitU, float* __restrict__ unitV) {
    int b = blockIdx.x;
    int t = threadIdx.x;

    if (b < 1024) {
        const float* src = (b < NBLK) ? rawU + (size_t)b * DDIM
                                      : rawV + (size_t)(b - NBLK) * DDIM;
        float* dst = (b < NBLK) ? unitU + (size_t)b * DDIM
                                : unitV + (size_t)(b - NBLK) * DDIM;
        float4 v = ((const float4*)src)[t];
        float ss = v.x * v.x + v.y * v.y + v.z * v.z + v.w * v.w;
        __shared__ float red[4];
        ss = wave_reduce_sum(ss);
        if ((t & 63) == 0) red[t >> 6] = ss;
        __syncthreads();
        float tot = red[0] + red[1] + red[2] + red[3];
        float inv = 1.f / fmaxf(sqrtf(tot), 1e-6f);
        float4 o;
        o.x = v.x * inv; o.y = v.y * inv; o.z = v.z * inv; o.w = v.w * inv;
        ((float4*)dst)[t] = o;
    } else if (b < 9216) {
        int n = b - 1024;
        float4 v = ((const float4*)(x + (size_t)n * DDIM))[t];
        float s1 = v.x + v.y + v.z + v.w;
        float s2 = v.x * v.x + v.y * v.y + v.z * v.z + v.w * v.w;
        __shared__ float r1[4], r2[4];
        s1 = wave_reduce_sum(s1);
        s2 = wave_reduce_sum(s2);
        if ((t & 63) == 0) { r1[t >> 6] = s1; r2[t >> 6] = s2; }
        __syncthreads();
        float mu  = (r1[0] + r1[1] + r1[2] + r1[3]) * (1.f / DDIM);
        float var = (r2[0] + r2[1] + r2[2] + r2[3]) * (1.f / DDIM) - mu * mu;
        float rstd = rsqrtf(var + 1e-5f);
        float4 g  = ((const float4*)ln_g)[t];
        float4 bb = ((const float4*)ln_b)[t];
        bf16x4 o, xo;
        o.x = (__bf16)((v.x - mu) * rstd * g.x + bb.x);
        o.y = (__bf16)((v.y - mu) * rstd * g.y + bb.y);
        o.z = (__bf16)((v.z - mu) * rstd * g.z + bb.z);
        o.w = (__bf16)((v.w - mu) * rstd * g.w + bb.w);
        xo.x = (__bf16)v.x; xo.y = (__bf16)v.y;
        xo.z = (__bf16)v.z; xo.w = (__bf16)v.w;
        ((bf16x4*)(lnb + (size_t)n * DDIM))[t] = o;
        ((bf16x4*)(xb  + (size_t)n * DDIM))[t] = xo;
    } else if (b < 13312) {
        cast1024(W1, w1b, (size_t)(b - 9216) * 1024, t);
    } else if (b < 17408) {
        cast1024(W2, w2b, (size_t)(b - 13312) * 1024, t);
    } else {
        cast1024(router_W, rwb, (size_t)(b - 17408) * 1024, t);
    }
}

// ---------------------------------------------------------------------------
// 2-phase 128xBN NT GEMM — router only (8.6 GFLOP).
// MODE 0: D = fast_softplus(clip(acc+bias)) -> fp32
// ---------------------------------------------------------------------------
template <int MODE, int BN>
__global__ __launch_bounds__(256) void mfma_gemm(const __bf16* __restrict__ A,
                                                 const __bf16* __restrict__ B,
                                                 const float* __restrict__ bias,
                                                 void* __restrict__ Cv,
                                                 int M, int Nn, int Kk) {
    constexpr int NJ  = BN / 32;
    constexpr int NQB = BN / 64;
    __shared__ __align__(16) __bf16 As[2][128 * 32];
    __shared__ __align__(16) __bf16 Bs[2][BN * 32];

    const int t    = threadIdx.x;
    const int lane = t & 63;
    const int wave = t >> 6;
    const int wm   = wave >> 1, wn = wave & 1;
    const int lr   = lane & 15, quad = lane >> 4;
    const int m0   = blockIdx.x * 128;
    const int n0   = blockIdx.y * BN;

    const int ca0 = t & 3;
    const __bf16* Ag[2];
    const __bf16* Bg[NQB];
    int ldsOffA[2], ldsOffB[NQB];
#pragma unroll
    for (int q = 0; q < 2; q++) {
        int idx = q * 256 + t;
        Ag[q]      = A + (size_t)(m0 + (idx >> 2)) * Kk + ca0 * 8;
        ldsOffA[q] = idx * 8;
    }
#pragma unroll
    for (int q = 0; q < NQB; q++) {
        int idx = q * 256 + t;
        Bg[q]      = B + (size_t)(n0 + (idx >> 2)) * Kk + ca0 * 8;
        ldsOffB[q] = idx * 8;
    }

    int raOff[4], rbOff[NJ];
#pragma unroll
    for (int i = 0; i < 4; i++)
        raOff[i] = (wm * 64 + i * 16 + lr) * 32 + quad * 8;
#pragma unroll
    for (int j = 0; j < NJ; j++)
        rbOff[j] = (wn * (BN / 2) + j * 16 + lr) * 32 + quad * 8;

    floatx4 acc[4][NJ];
#pragma unroll
    for (int i = 0; i < 4; i++)
#pragma unroll
        for (int j = 0; j < NJ; j++) acc[i][j] = (floatx4)0.f;

#pragma unroll
    for (int q = 0; q < 2; q++)   gload_lds16(Ag[q], &As[0][ldsOffA[q]]);
#pragma unroll
    for (int q = 0; q < NQB; q++) gload_lds16(Bg[q], &Bs[0][ldsOffB[q]]);

    const int niter = Kk >> 5;
    for (int it = 0; it < niter; ++it) {
        const int cur = it & 1;
        __syncthreads();
        if (it + 1 < niter) {
            const int nk = (it + 1) << 5;
            const int nb = cur ^ 1;
#pragma unroll
            for (int q = 0; q < 2; q++)   gload_lds16(Ag[q] + nk, &As[nb][ldsOffA[q]]);
#pragma unroll
            for (int q = 0; q < NQB; q++) gload_lds16(Bg[q] + nk, &Bs[nb][ldsOffB[q]]);
        }
        bf16x8 af[4], bfr[NJ];
#pragma unroll
        for (int i = 0; i < 4; i++)  af[i]  = *(const bf16x8*)&As[cur][raOff[i]];
#pragma unroll
        for (int j = 0; j < NJ; j++) bfr[j] = *(const bf16x8*)&Bs[cur][rbOff[j]];
#pragma unroll
        for (int i = 0; i < 4; i++)
#pragma unroll
            for (int j = 0; j < NJ; j++)
                acc[i][j] = __builtin_amdgcn_mfma_f32_16x16x32_bf16(af[i], bfr[j],
                                                                    acc[i][j], 0, 0, 0);
    }

    const int mBase = m0 + wm * 64 + quad * 4;
    const int nBase = n0 + wn * (BN / 2) + lr;
#pragma unroll
    for (int i = 0; i < 4; i++) {
#pragma unroll
        for (int j = 0; j < NJ; j++) {
            int n = nBase + j * 16;
#pragma unroll
            for (int r = 0; r < 4; r++) {
                int m = mBase + i * 16 + r;
                float v = acc[i][j][r];
                if (MODE == 0) {
                    float rr = v + bias[n];
                    rr = fminf(fmaxf(rr, -10.f), 10.f);
                    ((float*)Cv)[(size_t)m * Nn + n] = fast_softplus(rr);
                } else if (MODE == 1) {
                    ((__bf16*)Cv)[(size_t)m * Nn + n] = (__bf16)fast_gelu(v);
                } else {
                    ((float*)Cv)[(size_t)m * Nn + n] += v;
                }
            }
        }
    }
}

// ---------------------------------------------------------------------------
// 256x256 8-phase NT GEMM, BK=64, 512 thr = 8 waves (2M x 4N), wave 128x64.
// Snake: P0 MM(0,0)[12 rd], P1 MM(0,1)[4 rd], P2 MM(1,1)[8 rd], P3 MM(1,0)[0]
// = 24 ds_read_b128 / 64 MFMA. LDS XOR swizzle (0 bank conflicts).
// Best-measured configuration of the family (R1-R10 band: gemm2 105-122us,
// gemm1 ~85us). Schedule-invariant; see R9 verdict comment.
//   SCHED 0: vmcnt(10) at P0/P1/P3; tails (10/8/4), (2/0/0).
//   SCHED 1: lgkmcnt(8) hint at P0; single vmcnt(6) at P3; tails 0.
// MODE 1: D = gelu(acc)->bf16.  MODE 2: atomicAdd fp32 (split-K safe).
// ---------------------------------------------------------------------------
template <int MODE, int SPLITK, int SCHED>
__global__ __launch_bounds__(512, 2) void mfma_gemm8v2(const __bf16* __restrict__ A,
                                                       const __bf16* __restrict__ B,
                                                       void* __restrict__ Cv,
                                                       int M, int Nn, int Kk) {
    __shared__ __align__(16) __bf16 As[2][256 * 64];
    __shared__ __align__(16) __bf16 Bs[2][256 * 64];

    const int t    = threadIdx.x;
    const int lane = t & 63;
    const int wave = t >> 6;
    const int wm   = wave >> 2;        // 0..1
    const int wn   = wave & 3;         // 0..3
    const int lr   = lane & 15, quad = lane >> 4;

    // bijective XCD swizzle (gridDim.x % 8 == 0 by construction)
    const int nbn   = Nn >> 8;
    const int nmb   = M >> 8;
    const int chunk = gridDim.x >> 3;
    const int bid   = blockIdx.x;
    const int wg    = (bid & 7) * chunk + (bid >> 3);
    const int kslc  = wg / (nmb * nbn);
    const int rem   = wg % (nmb * nbn);
    const int m0    = (rem / nbn) * 256;
    const int n0    = (rem % nbn) * 256;
    const int kseg  = Kk / SPLITK;
    const int NT    = kseg >> 6;

    // ---- staging: linear LDS dest, inverse-swizzled global source ----
    const int srow = t >> 3;                               // 0..63
    const int scb  = ((t & 7) << 4) ^ ((srow & 7) << 4);   // swizzled byte col
    const __bf16* aP = A + (size_t)(m0 + srow) * Kk + (size_t)kslc * kseg + (scb >> 1);
    const __bf16* bP = B + (size_t)(n0 + srow) * Kk + (size_t)kslc * kseg + (scb >> 1);
    const int dP = srow * 64 + (t & 7) * 8;                // elems

    // ---- ds-read per-lane offsets (elements), swizzled ----
    int aRd[2], bRd[2];
#pragma unroll
    for (int ks = 0; ks < 2; ks++) {
        int sw = ((ks * 64 + quad * 16) ^ ((lr & 7) << 4)) >> 1;
        aRd[ks] = (wm * 64 + lr) * 64 + sw;
        bRd[ks] = (wn * 32 + lr) * 64 + sw;
    }

    floatx4 acc[8][4];
#pragma unroll
    for (int i = 0; i < 8; i++)
#pragma unroll
        for (int j = 0; j < 4; j++) acc[i][j] = (floatx4)0.f;

    bf16x8 af[4][2];        // A frags, current m-strip
    bf16x8 bfr0[2][2];      // B frags, n-strip 0 (held across tile)
    bf16x8 bfr1[2][2];      // B frags, n-strip 1

#define STAGE_A(KT, MH, BUF)                                                        \
    _Pragma("unroll") for (int q = 0; q < 2; q++)                                   \
        gload_lds16(aP + (size_t)(KT) * 64 + (size_t)(q * 64 + (MH) * 128) * Kk,    \
                    &As[BUF][dP + (q * 64 + (MH) * 128) * 64])
#define STAGE_B(KT, NH, BUF)                                                        \
    _Pragma("unroll") for (int q = 0; q < 2; q++)                                   \
        gload_lds16(bP + (size_t)(KT) * 64 + (size_t)(q * 64 + (NH) * 128) * Kk,    \
                    &Bs[BUF][dP + (q * 64 + (NH) * 128) * 64])
#define LDA(CUR, MH)                                                                \
    _Pragma("unroll") for (int ii = 0; ii < 4; ii++)                                \
    _Pragma("unroll") for (int ks = 0; ks < 2; ks++)                                \
        af[ii][ks] = *(const bf16x8*)&As[CUR][aRd[ks] + (MH) * 8192 + ii * 1024]
#define LDB(CUR, NH, DST)                                                           \
    _Pragma("unroll") for (int jj = 0; jj < 2; jj++)                                \
    _Pragma("unroll") for (int ks = 0; ks < 2; ks++)                                \
        DST[jj][ks] = *(const bf16x8*)&Bs[CUR][bRd[ks] + ((NH) * 128 + jj * 16) * 64]
#define MM(MH, NH, BFR)                                                             \
    _Pragma("unroll") for (int ii = 0; ii < 4; ii++)                                \
    _Pragma("unroll") for (int jj = 0; jj < 2; jj++)                                \
    _Pragma("unroll") for (int ks = 0; ks < 2; ks++)                                \
        acc[(MH) * 4 + ii][(NH) * 2 + jj] =                                         \
            __builtin_amdgcn_mfma_f32_16x16x32_bf16(                                \
                af[ii][ks], BFR[jj][ks], acc[(MH) * 4 + ii][(NH) * 2 + jj], 0, 0, 0)
#define VWAIT(NSTR) asm volatile("s_waitcnt vmcnt(" NSTR ")" ::: "memory")
#define LHINT()     asm volatile("s_waitcnt lgkmcnt(8)" ::: "memory")
#define WAITL()     asm volatile("s_waitcnt lgkmcnt(0)" ::: "memory")
#define BARR()      asm volatile("s_barrier" ::: "memory")
#define PRIO1()     __builtin_amdgcn_s_setprio(1)
#define PRIO0()     __builtin_amdgcn_s_setprio(0)

// R3-style: three counted waits per tile.
#define TILE3(KT, CUR, ST1, ST2, VM0, VM1, VM3)                                     \
    do {                                                                            \
        LDA(CUR, 0); LDB(CUR, 0, bfr0);                                             \
        if (ST1) { STAGE_A((KT) + 1, 1, ((KT) + 1) & 1); }                          \
        VWAIT(VM0); BARR(); WAITL();                                                \
        PRIO1(); MM(0, 0, bfr0); PRIO0(); BARR();                                   \
        LDB(CUR, 1, bfr1);                                                          \
        if (ST2) { STAGE_A((KT) + 2, 0, (KT) & 1); }                                \
        VWAIT(VM1); BARR(); WAITL();                                                \
        PRIO1(); MM(0, 1, bfr1); PRIO0(); BARR();                                   \
        LDA(CUR, 1);                                                                \
        if (ST2) { STAGE_B((KT) + 2, 0, (KT) & 1); }                                \
        BARR(); WAITL();                                                            \
        PRIO1(); MM(1, 1, bfr1); PRIO0(); BARR();                                   \
        if (ST2) { STAGE_B((KT) + 2, 1, (KT) & 1); }                                \
        VWAIT(VM3); BARR();                                                         \
        PRIO1(); MM(1, 0, bfr0); PRIO0(); BARR();                                   \
    } while (0)

// R4-style: single counted wait per tile at P3, lgkm hint at the 12-read phase.
#define TILE1(KT, CUR, ST1, ST2, VM)                                                \
    do {                                                                            \
        LDA(CUR, 0); LDB(CUR, 0, bfr0);                                             \
        if (ST1) { STAGE_A((KT) + 1, 1, ((KT) + 1) & 1); }                          \
        LHINT(); BARR(); WAITL();                                                   \
        PRIO1(); MM(0, 0, bfr0); PRIO0(); BARR();                                   \
        LDB(CUR, 1, bfr1);                                                          \
        if (ST2) { STAGE_A((KT) + 2, 0, (KT) & 1); }                                \
        BARR(); WAITL();                                                            \
        PRIO1(); MM(0, 1, bfr1); PRIO0(); BARR();                                   \
        LDA(CUR, 1);                                                                \
        if (ST2) { STAGE_B((KT) + 2, 0, (KT) & 1); }                                \
        BARR(); WAITL();                                                            \
        PRIO1(); MM(1, 1, bfr1); PRIO0(); BARR();                                   \
        if (ST2) { STAGE_B((KT) + 2, 1, (KT) & 1); }                                \
        VWAIT(VM); BARR();                                                          \
        PRIO1(); MM(1, 0, bfr0); PRIO0(); BARR();                                   \
    } while (0)

    // prologue: 7 half-tiles in consumption order [A0 B0 B1 A1]_t0 [A0 B0 B1]_t1
    STAGE_A(0, 0, 0); STAGE_B(0, 0, 0); STAGE_B(0, 1, 0); STAGE_A(0, 1, 0);
    STAGE_A(1, 0, 1); STAGE_B(1, 0, 1); STAGE_B(1, 1, 1);
    if (SCHED == 0) { VWAIT("10"); } else { VWAIT("6"); }
    BARR();

    if (SCHED == 0) {
        for (int kt = 0; kt < NT - 2; ++kt)
            TILE3(kt, kt & 1, true, true, "10", "10", "10");
        TILE3(NT - 2, (NT - 2) & 1, true, false, "10", "8", "4");
        TILE3(NT - 1, (NT - 1) & 1, false, false, "2", "0", "0");
    } else {
        for (int kt = 0; kt < NT - 2; ++kt)
            TILE1(kt, kt & 1, true, true, "6");
        TILE1(NT - 2, (NT - 2) & 1, true, false, "0");
        TILE1(NT - 1, (NT - 1) & 1, false, false, "0");
    }

#undef STAGE_A
#undef STAGE_B
#undef LDA
#undef LDB
#undef MM
#undef VWAIT
#undef LHINT
#undef WAITL
#undef BARR
#undef PRIO1
#undef PRIO0
#undef TILE3
#undef TILE1

    // ---- epilogue ----
#pragma unroll
    for (int i = 0; i < 8; i++) {
        const int mh = i >> 2, ii = i & 3;
#pragma unroll
        for (int j = 0; j < 4; j++) {
            const int nh = j >> 1, jj = j & 1;
            const int n = n0 + nh * 128 + wn * 32 + jj * 16 + lr;
#pragma unroll
            for (int r = 0; r < 4; r++) {
                const int m = m0 + mh * 128 + wm * 64 + ii * 16 + quad * 4 + r;
                const float v = acc[i][j][r];
                if (MODE == 1) {
                    ((__bf16*)Cv)[(size_t)m * Nn + n] = (__bf16)fast_gelu(v);
                } else {
                    atomicAdd(&((float*)Cv)[(size_t)m * Nn + n], v);
                }
            }
        }
    }
}

// ---------------------------------------------------------------------------
// Fused top-8 + dynamic path: ONE WAVE PER TOKEN (4 tokens / 256-thr block).
// R11 rewrite: the old per-token-block version had three runtime-indexed
// register arrays (v[gidx>>6], sidx[lane]=topi[lane], shz[lane]=topv[lane])
// -> scratch allocation (rule #20, localMem 5x cost), plus a serial top-8
// phase on 1 of 4 waves. Now: all indexing compile-time (elimination is an
// unrolled predicated compare), butterfly allreduce (every lane holds the
// sum), no LDS, no __syncthreads, float4 everywhere.
// ---------------------------------------------------------------------------
__global__ __launch_bounds__(256) void topk_dyn_kernel(
        const float* __restrict__ alpha,
        const float* __restrict__ x,
        const float* __restrict__ unitU,
        const float* __restrict__ unitV,
        const float* __restrict__ gamma,
        float* __restrict__ out) {
    const int lane = threadIdx.x & 63;
    const int wid  = threadIdx.x >> 6;
    const int n    = blockIdx.x * 4 + wid;

    // ---- load alpha row (512 floats, 8/lane) ----
    const float* row = alpha + (size_t)n * NBLK;
    float v[8];
#pragma unroll
    for (int i = 0; i < 8; i++) v[i] = row[lane + i * 64];

    // ---- top-8 selection, wave-parallel, compile-time indexing only ----
    float topv[8];
    int   topi[8];
#pragma unroll
    for (int s = 0; s < 8; s++) {
        float bv = v[0]; int bi = 0;
#pragma unroll
        for (int i = 1; i < 8; i++)
            if (v[i] > bv) { bv = v[i]; bi = i; }
        int gidx = lane + bi * 64;
#pragma unroll
        for (int off = 1; off < 64; off <<= 1) {
            float ov = __shfl_xor(bv, off, 64);
            int   oi = __shfl_xor(gidx, off, 64);
            if (ov > bv || (ov == bv && oi < gidx)) { bv = ov; gidx = oi; }
        }
        topv[s] = bv; topi[s] = gidx;      // uniform across the wave
        const int owner_lane = gidx & 63;
        const int owner_slot = gidx >> 6;
#pragma unroll
        for (int i = 0; i < 8; i++)
            if (i == owner_slot && lane == owner_lane) v[i] = -1e30f;
    }
    float S = 0.f;
#pragma unroll
    for (int s = 0; s < 8; s++) S += topv[s];
    const float zscale = tanhf(S) / (S + 1e-6f);

    // ---- h_k = <x, U_k>, all lanes participate; butterfly -> uniform ----
    const float4* xr4 = (const float4*)(x + (size_t)n * DDIM);
    float4 xv[4];
#pragma unroll
    for (int i = 0; i < 4; i++) xv[i] = xr4[lane + i * 64];

    float hz[8];
#pragma unroll
    for (int k = 0; k < 8; k++) {
        const float4* u4 = (const float4*)(unitU + (size_t)topi[k] * DDIM);
        float a = 0.f;
#pragma unroll
        for (int i = 0; i < 4; i++) {
            float4 u = u4[lane + i * 64];
            a = fmaf(xv[i].x, u.x, a);
            a = fmaf(xv[i].y, u.y, a);
            a = fmaf(xv[i].z, u.z, a);
            a = fmaf(xv[i].w, u.w, a);
        }
        a = wave_allreduce_sum(a);
        hz[k] = a * topv[k] * zscale;
    }

    // ---- out = (sum_k hz_k * V_k) * gamma ----
    const float4* g4 = (const float4*)gamma;
    float4* o4 = (float4*)(out + (size_t)n * DDIM);
#pragma unroll
    for (int i = 0; i < 4; i++) {
        float4 s4 = {0.f, 0.f, 0.f, 0.f};
#pragma unroll
        for (int k = 0; k < 8; k++) {
            float4 vv = ((const float4*)(unitV + (size_t)topi[k] * DDIM))[lane + i * 64];
            s4.x = fmaf(hz[k], vv.x, s4.x);
            s4.y = fmaf(hz[k], vv.y, s4.y);
            s4.z = fmaf(hz[k], vv.z, s4.z);
            s4.w = fmaf(hz[k], vv.w, s4.w);
        }
        float4 g = g4[lane + i * 64];
        float4 o;
        o.x = s4.x * g.x; o.y = s4.y * g.y; o.z = s4.z * g.z; o.w = s4.w * g.w;
        o4[lane + i * 64] = o;
    }
}

// ---------------------------------------------------------------------------
extern "C" void kernel_launch(void* const* d_in, const int* in_sizes, int n_in,
                              void* d_out, int out_size, void* d_ws, size_t ws_size,
                              hipStream_t stream) {
    const float* x        = (const float*)d_in[0];
    const float* W1       = (const float*)d_in[1];
    const float* W2       = (const float*)d_in[2];
    const float* ln_g     = (const float*)d_in[3];
    const float* ln_b     = (const float*)d_in[4];
    const float* router_W = (const float*)d_in[5];
    const float* router_b = (const float*)d_in[6];
    const float* raw_U    = (const float*)d_in[7];
    const float* raw_V    = (const float*)d_in[8];
    const float* gamma    = (const float*)d_in[9];
    float* out = (float*)d_out;

    char* ws = (char*)d_ws;
    __bf16* lnb   = (__bf16*)(ws);                 // 16,777,216 B
    float*  alpha = (float*)(ws + 16777216u);      // 16,777,216 B
    __bf16* g1    = (__bf16*)(ws);                 // 67,108,864 B (after topk_dyn)
    __bf16* xb    = (__bf16*)(ws + 67108864u);     // 16,777,216 B
    __bf16* w1b   = (__bf16*)(ws + 83886080u);     //  8,388,608 B
    __bf16* w2b   = (__bf16*)(ws + 92274688u);     //  8,388,608 B
    __bf16* rwb   = (__bf16*)(ws + 100663296u);    //  1,048,576 B
    float*  unitU = (float*)(ws + 101711872u);     //  2,097,152 B
    float*  unitV = (float*)(ws + 103809024u);     //  2,097,152 B

    prep_kernel<<<17920, 256, 0, stream>>>(x, ln_g, ln_b, W1, W2, router_W,
                                           raw_U, raw_V, xb, lnb, w1b, w2b, rwb,
                                           unitU, unitV);

    // router: [8192,512] = lnb @ rwb^T, softplus epilogue. BN=64 -> 512 blocks.
    dim3 gR(N_TOK / 128, NBLK / 64);
    mfma_gemm<0, 64><<<gR, 256, 0, stream>>>(lnb, rwb, router_b, (void*)alpha,
                                             N_TOK, NBLK, DDIM);

    // fused top-8 + dynamic path: 1 wave/token, 4 tokens/block -> 2048 blocks.
    topk_dyn_kernel<<<N_TOK / 4, 256, 0, stream>>>(alpha, x, unitU, unitV, gamma, out);

    // gemm1: g1 = gelu(x @ W1^T) -> bf16. 8-phase 256^2, SCHED=0. grid 512.
    mfma_gemm8v2<1, 1, 0><<<dim3(512), dim3(512), 0, stream>>>(xb, w1b, (void*)g1,
                                                               N_TOK, HDIM, DDIM);

    // gemm2: out += g1 @ W2^T. 8-phase 256^2, split-K=2, SCHED=1.
    // grid 32x4x2 -> 256 blocks, atomicAdd epilogue.
    mfma_gemm8v2<2, 2, 1><<<dim3(256), dim3(512), 0, stream>>>(g1, w2b, (void*)out,
                                                               N_TOK, DDIM, HDIM);
}

// Round 12
// 353.667 us; speedup vs baseline: 1.0322x; 1.0008x over previous
//
#include <hip/hip_runtime.h>
#include <hip/hip_bf16.h>
#include <math.h>

#define N_TOK 8192
#define DDIM  1024
#define HDIM  4096
#define NBLK  512

typedef __bf16 bf16x8 __attribute__((ext_vector_type(8)));
typedef __bf16 bf16x4 __attribute__((ext_vector_type(4)));
typedef float  floatx4 __attribute__((ext_vector_type(4)));

__device__ __forceinline__ float wave_reduce_sum(float v) {
#pragma unroll
    for (int off = 32; off > 0; off >>= 1) v += __shfl_down(v, off, 64);
    return v;
}

// Butterfly: every lane ends with the full sum (no broadcast needed).
__device__ __forceinline__ float wave_allreduce_sum(float v) {
#pragma unroll
    for (int off = 32; off > 0; off >>= 1) v += __shfl_xor(v, off, 64);
    return v;
}

__device__ __forceinline__ void gload_lds16(const void* g, void* l) {
    __builtin_amdgcn_global_load_lds((const __attribute__((address_space(1))) void*)g,
                                     (__attribute__((address_space(3))) void*)l,
                                     16, 0, 0);
}

// Branchless gelu via A&S 7.1.26 erf (max err 1.5e-7), ~13 VALU ops.
__device__ __forceinline__ float fast_gelu(float x) {
    float ax = fabsf(x);
    float z  = ax * 0.70710678118654752f;
    float t  = __builtin_amdgcn_rcpf(fmaf(0.3275911f, z, 1.0f));
    float p  = fmaf(fmaf(fmaf(fmaf(1.061405429f, t, -1.453152027f),
                              t, 1.421413741f),
                         t, -0.284496736f),
                    t, 0.254829592f);
    p *= t;
    float e = __expf(-z * z);
    float E = fmaf(-p, e, 1.0f);
    return 0.5f * fmaf(ax, E, x);
}

__device__ __forceinline__ float fast_softplus(float r) {
    return __logf(fmaf(1.0f, __expf(r), 1.0f));
}

// ---------------------------------------------------------------------------
// Fused prep kernel: unit rows / LN+x-cast / W casts.  All paths float4.
// ---------------------------------------------------------------------------
__device__ __forceinline__ void cast1024(const float* __restrict__ s,
                                         __bf16* __restrict__ d,
                                         size_t off, int t) {
    float4 v = ((const float4*)(s + off))[t];
    bf16x4 o;
    o.x = (__bf16)v.x; o.y = (__bf16)v.y;
    o.z = (__bf16)v.z; o.w = (__bf16)v.w;
    ((bf16x4*)(d + off))[t] = o;
}

__global__ __launch_bounds__(256) void prep_kernel(
        const float* __restrict__ x,
        const float* __restrict__ ln_g, const float* __restrict__ ln_b,
        const float* __restrict__ W1,   const float* __restrict__ W2,
        const float* __restrict__ router_W,
        const float* __restrict__ rawU, const float* __restrict__ rawV,
        __bf16* __restrict__ xb,  __bf16* __restrict__ lnb,
        __bf16* __restrict__ w1b, __bf16* __restrict__ w2b,
        __bf16* __restrict__ rwb,
        float* __restrict__ unitU, float* __restrict__ unitV) {
    int b = blockIdx.x;
    int t = threadIdx.x;

    if (b < 1024) {
        const float* src = (b < NBLK) ? rawU + (size_t)b * DDIM
                                      : rawV + (size_t)(b - NBLK) * DDIM;
        float* dst = (b < NBLK) ? unitU + (size_t)b * DDIM
                                : unitV + (size_t)(b - NBLK) * DDIM;
        float4 v = ((const float4*)src)[t];
        float ss = v.x * v.x + v.y * v.y + v.z * v.z + v.w * v.w;
        __shared__ float red[4];
        ss = wave_reduce_sum(ss);
        if ((t & 63) == 0) red[t >> 6] = ss;
        __syncthreads();
        float tot = red[0] + red[1] + red[2] + red[3];
        float inv = 1.f / fmaxf(sqrtf(tot), 1e-6f);
        float4 o;
        o.x = v.x * inv; o.y = v.y * inv; o.z = v.z * inv; o.w = v.w * inv;
        ((float4*)dst)[t] = o;
    } else if (b < 9216) {
        int n = b - 1024;
        float4 v = ((const float4*)(x + (size_t)n * DDIM))[t];
        float s1 = v.x + v.y + v.z + v.w;
        float s2 = v.x * v.x + v.y * v.y + v.z * v.z + v.w * v.w;
        __shared__ float r1[4], r2[4];
        s1 = wave_reduce_sum(s1);
        s2 = wave_reduce_sum(s2);
        if ((t & 63) == 0) { r1[t >> 6] = s1; r2[t >> 6] = s2; }
        __syncthreads();
        float mu  = (r1[0] + r1[1] + r1[2] + r1[3]) * (1.f / DDIM);
        float var = (r2[0] + r2[1] + r2[2] + r2[3]) * (1.f / DDIM) - mu * mu;
        float rstd = rsqrtf(var + 1e-5f);
        float4 g  = ((const float4*)ln_g)[t];
        float4 bb = ((const float4*)ln_b)[t];
        bf16x4 o, xo;
        o.x = (__bf16)((v.x - mu) * rstd * g.x + bb.x);
        o.y = (__bf16)((v.y - mu) * rstd * g.y + bb.y);
        o.z = (__bf16)((v.z - mu) * rstd * g.z + bb.z);
        o.w = (__bf16)((v.w - mu) * rstd * g.w + bb.w);
        xo.x = (__bf16)v.x; xo.y = (__bf16)v.y;
        xo.z = (__bf16)v.z; xo.w = (__bf16)v.w;
        ((bf16x4*)(lnb + (size_t)n * DDIM))[t] = o;
        ((bf16x4*)(xb  + (size_t)n * DDIM))[t] = xo;
    } else if (b < 13312) {
        cast1024(W1, w1b, (size_t)(b - 9216) * 1024, t);
    } else if (b < 17408) {
        cast1024(W2, w2b, (size_t)(b - 13312) * 1024, t);
    } else {
        cast1024(router_W, rwb, (size_t)(b - 17408) * 1024, t);
    }
}

// ---------------------------------------------------------------------------
// 2-phase 128xBN NT GEMM — router only (8.6 GFLOP).
// MODE 0: D = fast_softplus(clip(acc+bias)) -> fp32
// ---------------------------------------------------------------------------
template <int MODE, int BN>
__global__ __launch_bounds__(256) void mfma_gemm(const __bf16* __restrict__ A,
                                                 const __bf16* __restrict__ B,
                                                 const float* __restrict__ bias,
                                                 void* __restrict__ Cv,
                                                 int M, int Nn, int Kk) {
    constexpr int NJ  = BN / 32;
    constexpr int NQB = BN / 64;
    __shared__ __align__(16) __bf16 As[2][128 * 32];
    __shared__ __align__(16) __bf16 Bs[2][BN * 32];

    const int t    = threadIdx.x;
    const int lane = t & 63;
    const int wave = t >> 6;
    const int wm   = wave >> 1, wn = wave & 1;
    const int lr   = lane & 15, quad = lane >> 4;
    const int m0   = blockIdx.x * 128;
    const int n0   = blockIdx.y * BN;

    const int ca0 = t & 3;
    const __bf16* Ag[2];
    const __bf16* Bg[NQB];
    int ldsOffA[2], ldsOffB[NQB];
#pragma unroll
    for (int q = 0; q < 2; q++) {
        int idx = q * 256 + t;
        Ag[q]      = A + (size_t)(m0 + (idx >> 2)) * Kk + ca0 * 8;
        ldsOffA[q] = idx * 8;
    }
#pragma unroll
    for (int q = 0; q < NQB; q++) {
        int idx = q * 256 + t;
        Bg[q]      = B + (size_t)(n0 + (idx >> 2)) * Kk + ca0 * 8;
        ldsOffB[q] = idx * 8;
    }

    int raOff[4], rbOff[NJ];
#pragma unroll
    for (int i = 0; i < 4; i++)
        raOff[i] = (wm * 64 + i * 16 + lr) * 32 + quad * 8;
#pragma unroll
    for (int j = 0; j < NJ; j++)
        rbOff[j] = (wn * (BN / 2) + j * 16 + lr) * 32 + quad * 8;

    floatx4 acc[4][NJ];
#pragma unroll
    for (int i = 0; i < 4; i++)
#pragma unroll
        for (int j = 0; j < NJ; j++) acc[i][j] = (floatx4)0.f;

#pragma unroll
    for (int q = 0; q < 2; q++)   gload_lds16(Ag[q], &As[0][ldsOffA[q]]);
#pragma unroll
    for (int q = 0; q < NQB; q++) gload_lds16(Bg[q], &Bs[0][ldsOffB[q]]);

    const int niter = Kk >> 5;
    for (int it = 0; it < niter; ++it) {
        const int cur = it & 1;
        __syncthreads();
        if (it + 1 < niter) {
            const int nk = (it + 1) << 5;
            const int nb = cur ^ 1;
#pragma unroll
            for (int q = 0; q < 2; q++)   gload_lds16(Ag[q] + nk, &As[nb][ldsOffA[q]]);
#pragma unroll
            for (int q = 0; q < NQB; q++) gload_lds16(Bg[q] + nk, &Bs[nb][ldsOffB[q]]);
        }
        bf16x8 af[4], bfr[NJ];
#pragma unroll
        for (int i = 0; i < 4; i++)  af[i]  = *(const bf16x8*)&As[cur][raOff[i]];
#pragma unroll
        for (int j = 0; j < NJ; j++) bfr[j] = *(const bf16x8*)&Bs[cur][rbOff[j]];
#pragma unroll
        for (int i = 0; i < 4; i++)
#pragma unroll
            for (int j = 0; j < NJ; j++)
                acc[i][j] = __builtin_amdgcn_mfma_f32_16x16x32_bf16(af[i], bfr[j],
                                                                    acc[i][j], 0, 0, 0);
    }

    const int mBase = m0 + wm * 64 + quad * 4;
    const int nBase = n0 + wn * (BN / 2) + lr;
#pragma unroll
    for (int i = 0; i < 4; i++) {
#pragma unroll
        for (int j = 0; j < NJ; j++) {
            int n = nBase + j * 16;
#pragma unroll
            for (int r = 0; r < 4; r++) {
                int m = mBase + i * 16 + r;
                float v = acc[i][j][r];
                if (MODE == 0) {
                    float rr = v + bias[n];
                    rr = fminf(fmaxf(rr, -10.f), 10.f);
                    ((float*)Cv)[(size_t)m * Nn + n] = fast_softplus(rr);
                } else if (MODE == 1) {
                    ((__bf16*)Cv)[(size_t)m * Nn + n] = (__bf16)fast_gelu(v);
                } else {
                    ((float*)Cv)[(size_t)m * Nn + n] += v;
                }
            }
        }
    }
}

// ---------------------------------------------------------------------------
// 256x256 8-phase NT GEMM, BK=64, 512 thr = 8 waves (2M x 4N), wave 128x64.
// Snake: P0 MM(0,0)[12 rd], P1 MM(0,1)[4 rd], P2 MM(1,1)[8 rd], P3 MM(1,0)[0]
// = 24 ds_read_b128 / 64 MFMA. LDS XOR swizzle (0 bank conflicts).
// ATTRIBUTION FIX (R12): top-5 dispatches with WRITE=64MB/FETCH~49MB are
// GEMM1 (writes 64MB bf16 g1), not gemm2. gemm1 ~106us under both SCHEDs;
// gemm2@SCHED1+splitK < 106 (below top-5); gemm2@SCHED0 = 120.7 (R3).
// R12: MODE 1 epilogue rewritten as coalesced LDS-transit — old version
// issued 64 scalar 2B global stores/thread (32B coalesced runs, fully
// exposed at 1 block/CU). Now: wave-private 1280B patch in As (stride-40
// rows for bank spread), 8 ds_write_b16 -> lgkmcnt(0)+sched_barrier ->
// 1 ds_read_b128 + 1 global_store_dwordx4 per lane per (i,nh): 16 wide
// stores/thread, 64B runs. Wave-private => no __syncthreads (avoids
// vmcnt(0) draining in-flight stores); DS in-order per wave => no WAR.
//   SCHED 0: vmcnt(10) at P0/P1/P3; tails (10/8/4), (2/0/0).
//   SCHED 1: lgkmcnt(8) hint at P0; single vmcnt(6) at P3; tails 0.
// MODE 1: D = gelu(acc)->bf16.  MODE 2: atomicAdd fp32 (split-K safe).
// ---------------------------------------------------------------------------
template <int MODE, int SPLITK, int SCHED>
__global__ __launch_bounds__(512, 2) void mfma_gemm8v2(const __bf16* __restrict__ A,
                                                       const __bf16* __restrict__ B,
                                                       void* __restrict__ Cv,
                                                       int M, int Nn, int Kk) {
    __shared__ __align__(16) __bf16 As[2][256 * 64];
    __shared__ __align__(16) __bf16 Bs[2][256 * 64];

    const int t    = threadIdx.x;
    const int lane = t & 63;
    const int wave = t >> 6;
    const int wm   = wave >> 2;        // 0..1
    const int wn   = wave & 3;         // 0..3
    const int lr   = lane & 15, quad = lane >> 4;

    // bijective XCD swizzle (gridDim.x % 8 == 0 by construction)
    const int nbn   = Nn >> 8;
    const int nmb   = M >> 8;
    const int chunk = gridDim.x >> 3;
    const int bid   = blockIdx.x;
    const int wg    = (bid & 7) * chunk + (bid >> 3);
    const int kslc  = wg / (nmb * nbn);
    const int rem   = wg % (nmb * nbn);
    const int m0    = (rem / nbn) * 256;
    const int n0    = (rem % nbn) * 256;
    const int kseg  = Kk / SPLITK;
    const int NT    = kseg >> 6;

    // ---- staging: linear LDS dest, inverse-swizzled global source ----
    const int srow = t >> 3;                               // 0..63
    const int scb  = ((t & 7) << 4) ^ ((srow & 7) << 4);   // swizzled byte col
    const __bf16* aP = A + (size_t)(m0 + srow) * Kk + (size_t)kslc * kseg + (scb >> 1);
    const __bf16* bP = B + (size_t)(n0 + srow) * Kk + (size_t)kslc * kseg + (scb >> 1);
    const int dP = srow * 64 + (t & 7) * 8;                // elems

    // ---- ds-read per-lane offsets (elements), swizzled ----
    int aRd[2], bRd[2];
#pragma unroll
    for (int ks = 0; ks < 2; ks++) {
        int sw = ((ks * 64 + quad * 16) ^ ((lr & 7) << 4)) >> 1;
        aRd[ks] = (wm * 64 + lr) * 64 + sw;
        bRd[ks] = (wn * 32 + lr) * 64 + sw;
    }

    floatx4 acc[8][4];
#pragma unroll
    for (int i = 0; i < 8; i++)
#pragma unroll
        for (int j = 0; j < 4; j++) acc[i][j] = (floatx4)0.f;

    bf16x8 af[4][2];        // A frags, current m-strip
    bf16x8 bfr0[2][2];      // B frags, n-strip 0 (held across tile)
    bf16x8 bfr1[2][2];      // B frags, n-strip 1

#define STAGE_A(KT, MH, BUF)                                                        \
    _Pragma("unroll") for (int q = 0; q < 2; q++)                                   \
        gload_lds16(aP + (size_t)(KT) * 64 + (size_t)(q * 64 + (MH) * 128) * Kk,    \
                    &As[BUF][dP + (q * 64 + (MH) * 128) * 64])
#define STAGE_B(KT, NH, BUF)                                                        \
    _Pragma("unroll") for (int q = 0; q < 2; q++)                                   \
        gload_lds16(bP + (size_t)(KT) * 64 + (size_t)(q * 64 + (NH) * 128) * Kk,    \
                    &Bs[BUF][dP + (q * 64 + (NH) * 128) * 64])
#define LDA(CUR, MH)                                                                \
    _Pragma("unroll") for (int ii = 0; ii < 4; ii++)                                \
    _Pragma("unroll") for (int ks = 0; ks < 2; ks++)                                \
        af[ii][ks] = *(const bf16x8*)&As[CUR][aRd[ks] + (MH) * 8192 + ii * 1024]
#define LDB(CUR, NH, DST)                                                           \
    _Pragma("unroll") for (int jj = 0; jj < 2; jj++)                                \
    _Pragma("unroll") for (int ks = 0; ks < 2; ks++)                                \
        DST[jj][ks] = *(const bf16x8*)&Bs[CUR][bRd[ks] + ((NH) * 128 + jj * 16) * 64]
#define MM(MH, NH, BFR)                                                             \
    _Pragma("unroll") for (int ii = 0; ii < 4; ii++)                                \
    _Pragma("unroll") for (int jj = 0; jj < 2; jj++)                                \
    _Pragma("unroll") for (int ks = 0; ks < 2; ks++)                                \
        acc[(MH) * 4 + ii][(NH) * 2 + jj] =                                         \
            __builtin_amdgcn_mfma_f32_16x16x32_bf16(                                \
                af[ii][ks], BFR[jj][ks], acc[(MH) * 4 + ii][(NH) * 2 + jj], 0, 0, 0)
#define VWAIT(NSTR) asm volatile("s_waitcnt vmcnt(" NSTR ")" ::: "memory")
#define LHINT()     asm volatile("s_waitcnt lgkmcnt(8)" ::: "memory")
#define WAITL()     asm volatile("s_waitcnt lgkmcnt(0)" ::: "memory")
#define BARR()      asm volatile("s_barrier" ::: "memory")
#define PRIO1()     __builtin_amdgcn_s_setprio(1)
#define PRIO0()     __builtin_amdgcn_s_setprio(0)

// R3-style: three counted waits per tile.
#define TILE3(KT, CUR, ST1, ST2, VM0, VM1, VM3)                                     \
    do {                                                                            \
        LDA(CUR, 0); LDB(CUR, 0, bfr0);                                             \
        if (ST1) { STAGE_A((KT) + 1, 1, ((KT) + 1) & 1); }                          \
        VWAIT(VM0); BARR(); WAITL();                                                \
        PRIO1(); MM(0, 0, bfr0); PRIO0(); BARR();                                   \
        LDB(CUR, 1, bfr1);                                                          \
        if (ST2) { STAGE_A((KT) + 2, 0, (KT) & 1); }                                \
        VWAIT(VM1); BARR(); WAITL();                                                \
        PRIO1(); MM(0, 1, bfr1); PRIO0(); BARR();                                   \
        LDA(CUR, 1);                                                                \
        if (ST2) { STAGE_B((KT) + 2, 0, (KT) & 1); }                                \
        BARR(); WAITL();                                                            \
        PRIO1(); MM(1, 1, bfr1); PRIO0(); BARR();                                   \
        if (ST2) { STAGE_B((KT) + 2, 1, (KT) & 1); }                                \
        VWAIT(VM3); BARR();                                                         \
        PRIO1(); MM(1, 0, bfr0); PRIO0(); BARR();                                   \
    } while (0)

// R4-style: single counted wait per tile at P3, lgkm hint at the 12-read phase.
#define TILE1(KT, CUR, ST1, ST2, VM)                                                \
    do {                                                                            \
        LDA(CUR, 0); LDB(CUR, 0, bfr0);                                             \
        if (ST1) { STAGE_A((KT) + 1, 1, ((KT) + 1) & 1); }                          \
        LHINT(); BARR(); WAITL();                                                   \
        PRIO1(); MM(0, 0, bfr0); PRIO0(); BARR();                                   \
        LDB(CUR, 1, bfr1);                                                          \
        if (ST2) { STAGE_A((KT) + 2, 0, (KT) & 1); }                                \
        BARR(); WAITL();                                                            \
        PRIO1(); MM(0, 1, bfr1); PRIO0(); BARR();                                   \
        LDA(CUR, 1);                                                                \
        if (ST2) { STAGE_B((KT) + 2, 0, (KT) & 1); }                                \
        BARR(); WAITL();                                                            \
        PRIO1(); MM(1, 1, bfr1); PRIO0(); BARR();                                   \
        if (ST2) { STAGE_B((KT) + 2, 1, (KT) & 1); }                                \
        VWAIT(VM); BARR();                                                          \
        PRIO1(); MM(1, 0, bfr0); PRIO0(); BARR();                                   \
    } while (0)

    // prologue: 7 half-tiles in consumption order [A0 B0 B1 A1]_t0 [A0 B0 B1]_t1
    STAGE_A(0, 0, 0); STAGE_B(0, 0, 0); STAGE_B(0, 1, 0); STAGE_A(0, 1, 0);
    STAGE_A(1, 0, 1); STAGE_B(1, 0, 1); STAGE_B(1, 1, 1);
    if (SCHED == 0) { VWAIT("10"); } else { VWAIT("6"); }
    BARR();

    if (SCHED == 0) {
        for (int kt = 0; kt < NT - 2; ++kt)
            TILE3(kt, kt & 1, true, true, "10", "10", "10");
        TILE3(NT - 2, (NT - 2) & 1, true, false, "10", "8", "4");
        TILE3(NT - 1, (NT - 1) & 1, false, false, "2", "0", "0");
    } else {
        for (int kt = 0; kt < NT - 2; ++kt)
            TILE1(kt, kt & 1, true, true, "6");
        TILE1(NT - 2, (NT - 2) & 1, true, false, "0");
        TILE1(NT - 1, (NT - 1) & 1, false, false, "0");
    }

#undef STAGE_A
#undef STAGE_B
#undef LDA
#undef LDB
#undef MM
#undef VWAIT
#undef LHINT
#undef WAITL
#undef BARR
#undef PRIO1
#undef PRIO0
#undef TILE3
#undef TILE1

    // ---- epilogue ----
    if (MODE == 1) {
        // Coalesced LDS-transit epilogue: wave-private 16x(32+8pad) bf16 patch
        // (stride 40 elems = 80B rows -> writes ~4-way bank spread, reads
        // 16B-aligned). Per (i,nh): write 8 gelu'd values/lane, lgkmcnt(0),
        // read bf16x8/lane, one 16B global store (64B coalesced runs).
        __bf16* patch = &As[0][0] + wave * 640;   // 1280 B per wave
        const int prow = lane >> 2, pchunk = lane & 3;
#pragma unroll
        for (int i = 0; i < 8; i++) {
            const int mh = i >> 2, ii = i & 3;
#pragma unroll
            for (int nh = 0; nh < 2; nh++) {
#pragma unroll
                for (int jj = 0; jj < 2; jj++)
#pragma unroll
                    for (int r = 0; r < 4; r++)
                        patch[(quad * 4 + r) * 40 + jj * 16 + lr] =
                            (__bf16)fast_gelu(acc[i][nh * 2 + jj][r]);
                asm volatile("s_waitcnt lgkmcnt(0)" ::: "memory");
                __builtin_amdgcn_sched_barrier(0);
                bf16x8 vals = *(const bf16x8*)&patch[prow * 40 + pchunk * 8];
                const int m = m0 + mh * 128 + wm * 64 + ii * 16 + prow;
                const int n = n0 + nh * 128 + wn * 32 + pchunk * 8;
                *(bf16x8*)&((__bf16*)Cv)[(size_t)m * Nn + n] = vals;
            }
        }
    } else {
#pragma unroll
        for (int i = 0; i < 8; i++) {
            const int mh = i >> 2, ii = i & 3;
#pragma unroll
            for (int j = 0; j < 4; j++) {
                const int nh = j >> 1, jj = j & 1;
                const int n = n0 + nh * 128 + wn * 32 + jj * 16 + lr;
#pragma unroll
                for (int r = 0; r < 4; r++) {
                    const int m = m0 + mh * 128 + wm * 64 + ii * 16 + quad * 4 + r;
                    atomicAdd(&((float*)Cv)[(size_t)m * Nn + n], acc[i][j][r]);
                }
            }
        }
    }
}

// ---------------------------------------------------------------------------
// Fused top-8 + dynamic path: ONE WAVE PER TOKEN (4 tokens / 256-thr block).
// All indexing compile-time (rule #20: no scratch); butterfly allreduce;
// no LDS, no __syncthreads; float4 everywhere.  (R11: −16us vs block/token.)
// ---------------------------------------------------------------------------
__global__ __launch_bounds__(256) void topk_dyn_kernel(
        const float* __restrict__ alpha,
        const float* __restrict__ x,
        const float* __restrict__ unitU,
        const float* __restrict__ unitV,
        const float* __restrict__ gamma,
        float* __restrict__ out) {
    const int lane = threadIdx.x & 63;
    const int wid  = threadIdx.x >> 6;
    const int n    = blockIdx.x * 4 + wid;

    // ---- load alpha row (512 floats, 8/lane) ----
    const float* row = alpha + (size_t)n * NBLK;
    float v[8];
#pragma unroll
    for (int i = 0; i < 8; i++) v[i] = row[lane + i * 64];

    // ---- top-8 selection, wave-parallel, compile-time indexing only ----
    float topv[8];
    int   topi[8];
#pragma unroll
    for (int s = 0; s < 8; s++) {
        float bv = v[0]; int bi = 0;
#pragma unroll
        for (int i = 1; i < 8; i++)
            if (v[i] > bv) { bv = v[i]; bi = i; }
        int gidx = lane + bi * 64;
#pragma unroll
        for (int off = 1; off < 64; off <<= 1) {
            float ov = __shfl_xor(bv, off, 64);
            int   oi = __shfl_xor(gidx, off, 64);
            if (ov > bv || (ov == bv && oi < gidx)) { bv = ov; gidx = oi; }
        }
        topv[s] = bv; topi[s] = gidx;      // uniform across the wave
        const int owner_lane = gidx & 63;
        const int owner_slot = gidx >> 6;
#pragma unroll
        for (int i = 0; i < 8; i++)
            if (i == owner_slot && lane == owner_lane) v[i] = -1e30f;
    }
    float S = 0.f;
#pragma unroll
    for (int s = 0; s < 8; s++) S += topv[s];
    const float zscale = tanhf(S) / (S + 1e-6f);

    // ---- h_k = <x, U_k>, all lanes participate; butterfly -> uniform ----
    const float4* xr4 = (const float4*)(x + (size_t)n * DDIM);
    float4 xv[4];
#pragma unroll
    for (int i = 0; i < 4; i++) xv[i] = xr4[lane + i * 64];

    float hz[8];
#pragma unroll
    for (int k = 0; k < 8; k++) {
        const float4* u4 = (const float4*)(unitU + (size_t)topi[k] * DDIM);
        float a = 0.f;
#pragma unroll
        for (int i = 0; i < 4; i++) {
            float4 u = u4[lane + i * 64];
            a = fmaf(xv[i].x, u.x, a);
            a = fmaf(xv[i].y, u.y, a);
            a = fmaf(xv[i].z, u.z, a);
            a = fmaf(xv[i].w, u.w, a);
        }
        a = wave_allreduce_sum(a);
        hz[k] = a * topv[k] * zscale;
    }

    // ---- out = (sum_k hz_k * V_k) * gamma ----
    const float4* g4 = (const float4*)gamma;
    float4* o4 = (float4*)(out + (size_t)n * DDIM);
#pragma unroll
    for (int i = 0; i < 4; i++) {
        float4 s4 = {0.f, 0.f, 0.f, 0.f};
#pragma unroll
        for (int k = 0; k < 8; k++) {
            float4 vv = ((const float4*)(unitV + (size_t)topi[k] * DDIM))[lane + i * 64];
            s4.x = fmaf(hz[k], vv.x, s4.x);
            s4.y = fmaf(hz[k], vv.y, s4.y);
            s4.z = fmaf(hz[k], vv.z, s4.z);
            s4.w = fmaf(hz[k], vv.w, s4.w);
        }
        float4 g = g4[lane + i * 64];
        float4 o;
        o.x = s4.x * g.x; o.y = s4.y * g.y; o.z = s4.z * g.z; o.w = s4.w * g.w;
        o4[lane + i * 64] = o;
    }
}

// ---------------------------------------------------------------------------
extern "C" void kernel_launch(void* const* d_in, const int* in_sizes, int n_in,
                              void* d_out, int out_size, void* d_ws, size_t ws_size,
                              hipStream_t stream) {
    const float* x        = (const float*)d_in[0];
    const float* W1       = (const float*)d_in[1];
    const float* W2       = (const float*)d_in[2];
    const float* ln_g     = (const float*)d_in[3];
    const float* ln_b     = (const float*)d_in[4];
    const float* router_W = (const float*)d_in[5];
    const float* router_b = (const float*)d_in[6];
    const float* raw_U    = (const float*)d_in[7];
    const float* raw_V    = (const float*)d_in[8];
    const float* gamma    = (const float*)d_in[9];
    float* out = (float*)d_out;

    char* ws = (char*)d_ws;
    __bf16* lnb   = (__bf16*)(ws);                 // 16,777,216 B
    float*  alpha = (float*)(ws + 16777216u);      // 16,777,216 B
    __bf16* g1    = (__bf16*)(ws);                 // 67,108,864 B (after topk_dyn)
    __bf16* xb    = (__bf16*)(ws + 67108864u);     // 16,777,216 B
    __bf16* w1b   = (__bf16*)(ws + 83886080u);     //  8,388,608 B
    __bf16* w2b   = (__bf16*)(ws + 92274688u);     //  8,388,608 B
    __bf16* rwb   = (__bf16*)(ws + 100663296u);    //  1,048,576 B
    float*  unitU = (float*)(ws + 101711872u);     //  2,097,152 B
    float*  unitV = (float*)(ws + 103809024u);     //  2,097,152 B

    prep_kernel<<<17920, 256, 0, stream>>>(x, ln_g, ln_b, W1, W2, router_W,
                                           raw_U, raw_V, xb, lnb, w1b, w2b, rwb,
                                           unitU, unitV);

    // router: [8192,512] = lnb @ rwb^T, softplus epilogue. BN=64 -> 512 blocks.
    dim3 gR(N_TOK / 128, NBLK / 64);
    mfma_gemm<0, 64><<<gR, 256, 0, stream>>>(lnb, rwb, router_b, (void*)alpha,
                                             N_TOK, NBLK, DDIM);

    // fused top-8 + dynamic path: 1 wave/token, 4 tokens/block -> 2048 blocks.
    topk_dyn_kernel<<<N_TOK / 4, 256, 0, stream>>>(alpha, x, unitU, unitV, gamma, out);

    // gemm1: g1 = gelu(x @ W1^T) -> bf16. 8-phase 256^2, SCHED=0,
    // coalesced LDS-transit epilogue. grid 512.
    mfma_gemm8v2<1, 1, 0><<<dim3(512), dim3(512), 0, stream>>>(xb, w1b, (void*)g1,
                                                               N_TOK, HDIM, DDIM);

    // gemm2: out += g1 @ W2^T. 8-phase 256^2, split-K=2, SCHED=1.
    // grid 32x4x2 -> 256 blocks, atomicAdd epilogue.
    mfma_gemm8v2<2, 2, 1><<<dim3(256), dim3(512), 0, stream>>>(g1, w2b, (void*)out,
                                                               N_TOK, DDIM, HDIM);
}